// Round 1
// baseline (523.533 us; speedup 1.0000x reference)
//
#include <hip/hip_runtime.h>

// LimitedKVWithBBPM: scatter-add values into bbpm hash table, KV-cache
// position lookup for last K tokens, gather hit->cache / miss->bbpm.
// Entirely memory-bound; fp32 throughout.

constexpr int DIM    = 128;      // row width
constexpr int MEM    = 131072;   // BBPM_MEM_SIZE = 2^17 (power of two -> mask)
constexpr int KCACHE = 8192;     // KV_CACHE_SIZE

// 32 threads per row (float4 each), 8 rows per 256-thread block.
__global__ void scatter_kernel(const int* __restrict__ keys,
                               const float* __restrict__ vals,
                               float* __restrict__ acc, int n) {
    int row = blockIdx.x * 8 + (threadIdx.x >> 5);
    if (row >= n) return;
    int q = threadIdx.x & 31;
    unsigned slot = ((unsigned)keys[row]) & (MEM - 1);
    float4 v = *reinterpret_cast<const float4*>(vals + (size_t)row * DIM + q * 4);
    float* dst = acc + (size_t)slot * DIM + q * 4;
    atomicAdd(dst + 0, v.x);
    atomicAdd(dst + 1, v.y);
    atomicAdd(dst + 2, v.z);
    atomicAdd(dst + 3, v.w);
}

// pos_table[positions[n-K+j]] = j  for j in [0,K)
__global__ void build_pos_kernel(const int* __restrict__ positions,
                                 int* __restrict__ pos_table, int n, int K) {
    int j = blockIdx.x * 256 + threadIdx.x;
    if (j >= K) return;
    int p = positions[n - K + j];
    if (p >= 0 && p < n) pos_table[p] = j;
}

// out[row] = hit ? vals[base+idx] : acc[qkey & (MEM-1)]
__global__ void gather_kernel(const float* __restrict__ vals,
                              const float* __restrict__ acc,
                              const int* __restrict__ qkeys,
                              const int* __restrict__ qpos,
                              const int* __restrict__ pos_table,
                              float* __restrict__ out, int n, int base) {
    int row = blockIdx.x * 8 + (threadIdx.x >> 5);
    if (row >= n) return;
    int q = threadIdx.x & 31;
    int qp = qpos[row];
    int idx = (qp >= 0 && qp < n) ? pos_table[qp] : -1;
    const float* src;
    if (idx >= 0) {
        src = vals + (size_t)(base + idx) * DIM;
    } else {
        unsigned slot = ((unsigned)qkeys[row]) & (MEM - 1);
        src = acc + (size_t)slot * DIM;
    }
    float4 v = *reinterpret_cast<const float4*>(src + q * 4);
    *reinterpret_cast<float4*>(out + (size_t)row * DIM + q * 4) = v;
}

extern "C" void kernel_launch(void* const* d_in, const int* in_sizes, int n_in,
                              void* d_out, int out_size, void* d_ws, size_t ws_size,
                              hipStream_t stream) {
    const int*   keys      = (const int*)d_in[0];
    const float* vals      = (const float*)d_in[1];
    const int*   positions = (const int*)d_in[2];
    const int*   qkeys     = (const int*)d_in[3];
    const int*   qpos      = (const int*)d_in[4];
    const float* bbpm      = (const float*)d_in[5];
    float* out = (float*)d_out;

    const int n = in_sizes[0];                 // total tokens (B*T)
    const size_t acc_bytes = (size_t)MEM * DIM * sizeof(float);   // 64 MiB

    float* acc       = (float*)d_ws;
    int*   pos_table = (int*)((char*)d_ws + acc_bytes);

    // Seed accumulator with bbpm_mem (reference: mem = bbpm_mem + scatter).
    hipMemcpyAsync(acc, bbpm, acc_bytes, hipMemcpyDeviceToDevice, stream);
    // pos_table = -1 everywhere (0xFF bytes -> -1 int32).
    hipMemsetAsync(pos_table, 0xFF, (size_t)n * sizeof(int), stream);

    scatter_kernel<<<(n + 7) / 8, 256, 0, stream>>>(keys, vals, acc, n);
    build_pos_kernel<<<(KCACHE + 255) / 256, 256, 0, stream>>>(positions, pos_table, n, KCACHE);
    gather_kernel<<<(n + 7) / 8, 256, 0, stream>>>(vals, acc, qkeys, qpos, pos_table,
                                                   out, n, n - KCACHE);
}

// Round 2
// 143.735 us; speedup vs baseline: 3.6424x; 3.6424x over previous
//
#include <hip/hip_runtime.h>

// LimitedKVWithBBPM — round 2.
// Replace fp32 atomic scatter (512 MB HBM write amplification, 445 us) with
// counting-bucket gather-reduce: int-atomic bucket fill (L2-resident counters),
// then per-slot sum of ~2 value rows + bbpm seed, single write per slot.
// Overflow fallback keeps generic correctness for adversarial key distributions.

constexpr int DIM    = 128;      // row width
constexpr int MEM    = 131072;   // BBPM_MEM_SIZE = 2^17 -> mask
constexpr int KCACHE = 8192;     // KV_CACHE_SIZE
constexpr int CAP    = 16;       // bucket capacity per slot (mean load = 2)

// One thread per token: slot = key & mask, claim a bucket position.
__global__ void fill_kernel(const int* __restrict__ keys,
                            int* __restrict__ cnt,
                            int* __restrict__ bucket,
                            int* __restrict__ ovf_cnt,
                            int* __restrict__ ovf,
                            int n) {
    int i = blockIdx.x * 256 + threadIdx.x;
    if (i >= n) return;
    int slot = ((unsigned)keys[i]) & (MEM - 1);
    int pos = atomicAdd(&cnt[slot], 1);
    if (pos < CAP) {
        bucket[slot * CAP + pos] = i;
    } else {
        int k = atomicAdd(ovf_cnt, 1);
        ovf[k] = i;
    }
}

// pos_table[positions[n-K+j]] = j  for j in [0,K)
__global__ void build_pos_kernel(const int* __restrict__ positions,
                                 int* __restrict__ pos_table, int n, int K) {
    int j = blockIdx.x * 256 + threadIdx.x;
    if (j >= K) return;
    int p = positions[n - K + j];
    if (p >= 0 && p < n) pos_table[p] = j;
}

// One 32-thread group per slot: acc[slot] = bbpm[slot] + sum(vals[bucket[slot]]).
// 8 slots per 256-thread block.
__global__ void reduce_kernel(const float* __restrict__ vals,
                              const float* __restrict__ bbpm,
                              const int* __restrict__ cnt,
                              const int* __restrict__ bucket,
                              float* __restrict__ acc) {
    int slot = blockIdx.x * 8 + (threadIdx.x >> 5);
    int q = threadIdx.x & 31;
    int c = cnt[slot];
    if (c > CAP) c = CAP;                 // overflow entries handled separately
    float4 s = *reinterpret_cast<const float4*>(bbpm + (size_t)slot * DIM + q * 4);
    for (int j = 0; j < c; ++j) {
        int row = bucket[slot * CAP + j];
        float4 v = *reinterpret_cast<const float4*>(vals + (size_t)row * DIM + q * 4);
        s.x += v.x; s.y += v.y; s.z += v.z; s.w += v.w;
    }
    *reinterpret_cast<float4*>(acc + (size_t)slot * DIM + q * 4) = s;
}

// Rare path: tokens that overflowed CAP get atomic-added after the reduce.
// Expected zero iterations for ~uniform keys; exists for generic correctness.
__global__ void overflow_kernel(const float* __restrict__ vals,
                                const int* __restrict__ keys,
                                const int* __restrict__ ovf_cnt,
                                const int* __restrict__ ovf,
                                float* __restrict__ acc) {
    int total = *ovf_cnt;
    int tid = blockIdx.x * 256 + threadIdx.x;
    int stride = gridDim.x * 256;
    for (int w = tid; w < total * 32; w += stride) {
        int e = w >> 5, q = w & 31;
        int i = ovf[e];
        int slot = ((unsigned)keys[i]) & (MEM - 1);
        float4 v = *reinterpret_cast<const float4*>(vals + (size_t)i * DIM + q * 4);
        float* dst = acc + (size_t)slot * DIM + q * 4;
        atomicAdd(dst + 0, v.x);
        atomicAdd(dst + 1, v.y);
        atomicAdd(dst + 2, v.z);
        atomicAdd(dst + 3, v.w);
    }
}

// out[row] = hit ? vals[base+idx] : acc[qkey & mask]
__global__ void gather_kernel(const float* __restrict__ vals,
                              const float* __restrict__ acc,
                              const int* __restrict__ qkeys,
                              const int* __restrict__ qpos,
                              const int* __restrict__ pos_table,
                              float* __restrict__ out, int n, int base) {
    int row = blockIdx.x * 8 + (threadIdx.x >> 5);
    if (row >= n) return;
    int q = threadIdx.x & 31;
    int qp = qpos[row];
    int idx = (qp >= 0 && qp < n) ? pos_table[qp] : -1;
    const float* src;
    if (idx >= 0) {
        src = vals + (size_t)(base + idx) * DIM;
    } else {
        unsigned slot = ((unsigned)qkeys[row]) & (MEM - 1);
        src = acc + (size_t)slot * DIM;
    }
    float4 v = *reinterpret_cast<const float4*>(src + q * 4);
    *reinterpret_cast<float4*>(out + (size_t)row * DIM + q * 4) = v;
}

extern "C" void kernel_launch(void* const* d_in, const int* in_sizes, int n_in,
                              void* d_out, int out_size, void* d_ws, size_t ws_size,
                              hipStream_t stream) {
    const int*   keys      = (const int*)d_in[0];
    const float* vals      = (const float*)d_in[1];
    const int*   positions = (const int*)d_in[2];
    const int*   qkeys     = (const int*)d_in[3];
    const int*   qpos      = (const int*)d_in[4];
    const float* bbpm      = (const float*)d_in[5];
    float* out = (float*)d_out;

    const int n = in_sizes[0];                              // B*T tokens
    const size_t acc_bytes = (size_t)MEM * DIM * sizeof(float);   // 64 MiB

    // d_ws layout (all 256B-aligned):
    char* ws = (char*)d_ws;
    float* acc       = (float*)ws;                           // 64 MiB
    int*   pos_table = (int*)(ws + acc_bytes);               // n*4 = 1 MiB
    int*   cnt       = (int*)(ws + acc_bytes + (size_t)n * 4);        // 512 KiB
    int*   ovf_cnt   = (int*)((char*)cnt + (size_t)MEM * 4);          // 256 B
    int*   ovf       = (int*)((char*)ovf_cnt + 256);                  // n*4

    // Buckets live in d_out (8 MiB of 134 MiB); gather fully overwrites later.
    int* bucket = (int*)d_out;

    // Zero counters (cnt + ovf_cnt in one memset range), pos_table = -1.
    hipMemsetAsync(cnt, 0, (size_t)MEM * 4 + 256, stream);
    hipMemsetAsync(pos_table, 0xFF, (size_t)n * sizeof(int), stream);

    fill_kernel<<<(n + 255) / 256, 256, 0, stream>>>(keys, cnt, bucket, ovf_cnt, ovf, n);
    build_pos_kernel<<<(KCACHE + 255) / 256, 256, 0, stream>>>(positions, pos_table, n, KCACHE);
    reduce_kernel<<<MEM / 8, 256, 0, stream>>>(vals, bbpm, cnt, bucket, acc);
    overflow_kernel<<<64, 256, 0, stream>>>(vals, keys, ovf_cnt, ovf, acc);
    gather_kernel<<<(n + 7) / 8, 256, 0, stream>>>(vals, acc, qkeys, qpos, pos_table,
                                                   out, n, n - KCACHE);
}

// Round 3
// 134.958 us; speedup vs baseline: 3.8792x; 1.0650x over previous
//
#include <hip/hip_runtime.h>

// LimitedKVWithBBPM — round 3.
// Round-2 counters: reduce is latency-bound (91 us even when L3-resident),
// not BW-bound. This round maximizes memory-level parallelism: batched bucket
// metadata + multiple row-chains in flight per wave in both reduce and gather.

constexpr int DIM    = 128;      // row width
constexpr int MEM    = 131072;   // BBPM_MEM_SIZE = 2^17 -> mask
constexpr int KCACHE = 8192;     // KV_CACHE_SIZE
constexpr int CAP    = 16;       // bucket capacity per slot (mean load = 2)

__device__ __forceinline__ float4 ldrow(const float* __restrict__ p, int q) {
    return *reinterpret_cast<const float4*>(p + q * 4);
}

// One thread per token: slot = key & mask, claim a bucket position.
__global__ void fill_kernel(const int* __restrict__ keys,
                            int* __restrict__ cnt,
                            int* __restrict__ bucket,
                            int* __restrict__ ovf_cnt,
                            int* __restrict__ ovf,
                            int n) {
    int i = blockIdx.x * 256 + threadIdx.x;
    if (i >= n) return;
    int slot = ((unsigned)keys[i]) & (MEM - 1);
    int pos = atomicAdd(&cnt[slot], 1);
    if (pos < CAP) {
        bucket[slot * CAP + pos] = i;
    } else {
        int k = atomicAdd(ovf_cnt, 1);
        ovf[k] = i;
    }
}

// pos_table[positions[n-K+j]] = j  for j in [0,K)
__global__ void build_pos_kernel(const int* __restrict__ positions,
                                 int* __restrict__ pos_table, int n, int K) {
    int j = blockIdx.x * 256 + threadIdx.x;
    if (j >= K) return;
    int p = positions[n - K + j];
    if (p >= 0 && p < n) pos_table[p] = j;
}

// Each 32-lane group handles 2 slots (s, s+8); block of 256 covers 16 slots.
// All metadata loads first, then up to 6 row loads in flight, masked adds.
__global__ void reduce_kernel(const float* __restrict__ vals,
                              const float* __restrict__ bbpm,
                              const int* __restrict__ cnt,
                              const int* __restrict__ bucket,
                              float* __restrict__ acc) {
    int g = threadIdx.x >> 5;
    int q = threadIdx.x & 31;
    int s0 = blockIdx.x * 16 + g;
    int s1 = s0 + 8;

    int c0 = cnt[s0]; if (c0 > CAP) c0 = CAP;
    int c1 = cnt[s1]; if (c1 > CAP) c1 = CAP;
    int4 b0 = reinterpret_cast<const int4*>(bucket)[s0 * 4];
    int4 b1 = reinterpret_cast<const int4*>(bucket)[s1 * 4];

    // Predicate invalid rows to row 0 (L2-hot after first touch, no extra HBM)
    int r00 = c0 > 0 ? b0.x : 0, r01 = c0 > 1 ? b0.y : 0;
    int r10 = c1 > 0 ? b1.x : 0, r11 = c1 > 1 ? b1.y : 0;
    float m00 = c0 > 0 ? 1.f : 0.f, m01 = c0 > 1 ? 1.f : 0.f;
    float m10 = c1 > 0 ? 1.f : 0.f, m11 = c1 > 1 ? 1.f : 0.f;

    float4 A0  = ldrow(bbpm + (size_t)s0  * DIM, q);
    float4 A1  = ldrow(bbpm + (size_t)s1  * DIM, q);
    float4 V00 = ldrow(vals + (size_t)r00 * DIM, q);
    float4 V01 = ldrow(vals + (size_t)r01 * DIM, q);
    float4 V10 = ldrow(vals + (size_t)r10 * DIM, q);
    float4 V11 = ldrow(vals + (size_t)r11 * DIM, q);

    float4 a0, a1;
    a0.x = A0.x + m00 * V00.x + m01 * V01.x;
    a0.y = A0.y + m00 * V00.y + m01 * V01.y;
    a0.z = A0.z + m00 * V00.z + m01 * V01.z;
    a0.w = A0.w + m00 * V00.w + m01 * V01.w;
    a1.x = A1.x + m10 * V10.x + m11 * V11.x;
    a1.y = A1.y + m10 * V10.y + m11 * V11.y;
    a1.z = A1.z + m10 * V10.z + m11 * V11.z;
    a1.w = A1.w + m10 * V10.w + m11 * V11.w;

    // Rare tails (P(c>2) ~ 0.32): indices 2,3 already in registers.
    if (c0 > 2) {
        float4 v = ldrow(vals + (size_t)b0.z * DIM, q);
        a0.x += v.x; a0.y += v.y; a0.z += v.z; a0.w += v.w;
        if (c0 > 3) {
            v = ldrow(vals + (size_t)b0.w * DIM, q);
            a0.x += v.x; a0.y += v.y; a0.z += v.z; a0.w += v.w;
            for (int j = 4; j < c0; ++j) {
                int r = bucket[s0 * CAP + j];
                v = ldrow(vals + (size_t)r * DIM, q);
                a0.x += v.x; a0.y += v.y; a0.z += v.z; a0.w += v.w;
            }
        }
    }
    if (c1 > 2) {
        float4 v = ldrow(vals + (size_t)b1.z * DIM, q);
        a1.x += v.x; a1.y += v.y; a1.z += v.z; a1.w += v.w;
        if (c1 > 3) {
            v = ldrow(vals + (size_t)b1.w * DIM, q);
            a1.x += v.x; a1.y += v.y; a1.z += v.z; a1.w += v.w;
            for (int j = 4; j < c1; ++j) {
                int r = bucket[s1 * CAP + j];
                v = ldrow(vals + (size_t)r * DIM, q);
                a1.x += v.x; a1.y += v.y; a1.z += v.z; a1.w += v.w;
            }
        }
    }

    *reinterpret_cast<float4*>(acc + (size_t)s0 * DIM + q * 4) = a0;
    *reinterpret_cast<float4*>(acc + (size_t)s1 * DIM + q * 4) = a1;
}

// Rare path: tokens that overflowed CAP get atomic-added after the reduce.
__global__ void overflow_kernel(const float* __restrict__ vals,
                                const int* __restrict__ keys,
                                const int* __restrict__ ovf_cnt,
                                const int* __restrict__ ovf,
                                float* __restrict__ acc) {
    int total = *ovf_cnt;
    int tid = blockIdx.x * 256 + threadIdx.x;
    int stride = gridDim.x * 256;
    for (int w = tid; w < total * 32; w += stride) {
        int e = w >> 5, q = w & 31;
        int i = ovf[e];
        int slot = ((unsigned)keys[i]) & (MEM - 1);
        float4 v = ldrow(vals + (size_t)i * DIM, q);
        float* dst = acc + (size_t)slot * DIM + q * 4;
        atomicAdd(dst + 0, v.x);
        atomicAdd(dst + 1, v.y);
        atomicAdd(dst + 2, v.z);
        atomicAdd(dst + 3, v.w);
    }
}

// Each 32-lane group handles 4 output rows (r, r+8, r+16, r+24);
// all pos_table hops issued together, then all 4 row loads together.
__global__ void gather_kernel(const float* __restrict__ vals,
                              const float* __restrict__ acc,
                              const int* __restrict__ qkeys,
                              const int* __restrict__ qpos,
                              const int* __restrict__ pos_table,
                              float* __restrict__ out, int n, int base) {
    int g = threadIdx.x >> 5;
    int q = threadIdx.x & 31;
    int r0 = blockIdx.x * 32 + g;
    int r1 = r0 + 8, r2 = r0 + 16, r3 = r0 + 24;

    bool k0 = r0 < n, k1 = r1 < n, k2 = r2 < n, k3 = r3 < n;
    int qp0 = k0 ? qpos[r0] : -1, qp1 = k1 ? qpos[r1] : -1;
    int qp2 = k2 ? qpos[r2] : -1, qp3 = k3 ? qpos[r3] : -1;
    int qk0 = k0 ? qkeys[r0] : 0, qk1 = k1 ? qkeys[r1] : 0;
    int qk2 = k2 ? qkeys[r2] : 0, qk3 = k3 ? qkeys[r3] : 0;

    int i0 = (qp0 >= 0 && qp0 < n) ? pos_table[qp0] : -1;
    int i1 = (qp1 >= 0 && qp1 < n) ? pos_table[qp1] : -1;
    int i2 = (qp2 >= 0 && qp2 < n) ? pos_table[qp2] : -1;
    int i3 = (qp3 >= 0 && qp3 < n) ? pos_table[qp3] : -1;

    const float* s0 = (i0 >= 0) ? vals + (size_t)(base + i0) * DIM
                                : acc + (size_t)(((unsigned)qk0) & (MEM - 1)) * DIM;
    const float* s1 = (i1 >= 0) ? vals + (size_t)(base + i1) * DIM
                                : acc + (size_t)(((unsigned)qk1) & (MEM - 1)) * DIM;
    const float* s2 = (i2 >= 0) ? vals + (size_t)(base + i2) * DIM
                                : acc + (size_t)(((unsigned)qk2) & (MEM - 1)) * DIM;
    const float* s3 = (i3 >= 0) ? vals + (size_t)(base + i3) * DIM
                                : acc + (size_t)(((unsigned)qk3) & (MEM - 1)) * DIM;

    float4 v0 = ldrow(s0, q);
    float4 v1 = ldrow(s1, q);
    float4 v2 = ldrow(s2, q);
    float4 v3 = ldrow(s3, q);

    if (k0) *reinterpret_cast<float4*>(out + (size_t)r0 * DIM + q * 4) = v0;
    if (k1) *reinterpret_cast<float4*>(out + (size_t)r1 * DIM + q * 4) = v1;
    if (k2) *reinterpret_cast<float4*>(out + (size_t)r2 * DIM + q * 4) = v2;
    if (k3) *reinterpret_cast<float4*>(out + (size_t)r3 * DIM + q * 4) = v3;
}

extern "C" void kernel_launch(void* const* d_in, const int* in_sizes, int n_in,
                              void* d_out, int out_size, void* d_ws, size_t ws_size,
                              hipStream_t stream) {
    const int*   keys      = (const int*)d_in[0];
    const float* vals      = (const float*)d_in[1];
    const int*   positions = (const int*)d_in[2];
    const int*   qkeys     = (const int*)d_in[3];
    const int*   qpos      = (const int*)d_in[4];
    const float* bbpm      = (const float*)d_in[5];
    float* out = (float*)d_out;

    const int n = in_sizes[0];                              // B*T tokens
    const size_t acc_bytes = (size_t)MEM * DIM * sizeof(float);   // 64 MiB

    char* ws = (char*)d_ws;
    float* acc       = (float*)ws;                                    // 64 MiB
    int*   pos_table = (int*)(ws + acc_bytes);                        // n*4
    int*   cnt       = (int*)(ws + acc_bytes + (size_t)n * 4);        // 512 KiB
    int*   ovf_cnt   = (int*)((char*)cnt + (size_t)MEM * 4);          // 256 B
    int*   ovf       = (int*)((char*)ovf_cnt + 256);                  // n*4

    // Buckets live in d_out (8 MiB of 134 MiB); gather fully overwrites later.
    int* bucket = (int*)d_out;

    hipMemsetAsync(cnt, 0, (size_t)MEM * 4 + 256, stream);
    hipMemsetAsync(pos_table, 0xFF, (size_t)n * sizeof(int), stream);

    fill_kernel<<<(n + 255) / 256, 256, 0, stream>>>(keys, cnt, bucket, ovf_cnt, ovf, n);
    build_pos_kernel<<<(KCACHE + 255) / 256, 256, 0, stream>>>(positions, pos_table, n, KCACHE);
    reduce_kernel<<<MEM / 16, 256, 0, stream>>>(vals, bbpm, cnt, bucket, acc);
    overflow_kernel<<<64, 256, 0, stream>>>(vals, keys, ovf_cnt, ovf, acc);
    gather_kernel<<<(n + 31) / 32, 256, 0, stream>>>(vals, acc, qkeys, qpos, pos_table,
                                                     out, n, n - KCACHE);
}